// Round 1
// baseline (382.453 us; speedup 1.0000x reference)
//
#include <hip/hip_runtime.h>
#include <math.h>

// Problem constants
#define NN  8
#define CIc 8
#define DIc 8
#define Hh  48
#define Ww  48
#define COo 16
#define DOo 16
#define HW  2304      // 48*48
#define HP  52
#define WP  52
#define KT  200       // DIc*5*5

// Workspace layout (float offsets). Total = 46,915,584 floats = ~180 MB.
#define OFF_UP   0
#define SZ_UP    (NN*CIc*DIc*HP*WP)          // 1,384,448
#define OFF_WT   (OFF_UP + SZ_UP)
#define SZ_WT    (CIc*COo*KT*DOo)            // 409,600
#define OFF_UH   (OFF_WT + SZ_WT)
#define SZ_UH    (NN*CIc*COo*DOo*HW)         // 37,748,736
#define OFF_B    (OFF_UH + SZ_UH)
#define SZ_B     (NN*CIc*COo*HW)             // 2,359,296
#define OFF_BM   (OFF_B + SZ_B)
#define SZ_BM    (NN*CIc*HW)                 // 147,456
#define OFF_IS   (OFF_BM + SZ_BM)
#define SZ_IS    (NN*CIc*HW)
#define OFF_V    (OFF_IS + SZ_IS)
#define SZ_V     (NN*COo*DOo*HW)             // 4,718,592

// ---------------------------------------------------------------- pad u
__global__ __launch_bounds__(256) void pad_u_k(const float* __restrict__ u,
                                               float* __restrict__ up) {
  int idx = blockIdx.x * 256 + threadIdx.x;
  if (idx >= SZ_UP) return;
  int pw = idx % WP;
  int t  = idx / WP;
  int ph = t % HP;
  t /= HP;                       // t = (n*CIc+ci)*DIc+di
  int h = ph - 2, w = pw - 2;
  float val = 0.f;
  if (h >= 0 && h < Hh && w >= 0 && w < Ww)
    val = u[(size_t)t * (Hh * Ww) + h * Ww + w];
  up[idx] = val;
}

// ------------------------------------------------------------ transpose w
// wT[(ci*COo+co)*KT + t][do] = w[(ci*256 + co*16 + do)*KT + t]
__global__ __launch_bounds__(256) void transpose_w_k(const float* __restrict__ w,
                                                     float* __restrict__ wT) {
  int idx = blockIdx.x * 256 + threadIdx.x;
  if (idx >= SZ_WT) return;
  int dd = idx % DOo;
  int t2 = idx / DOo;
  int t  = t2 % KT;
  t2 /= KT;
  int co = t2 % COo;
  int ci = t2 / COo;
  wT[idx] = w[(size_t)(ci * (COo * DOo) + co * DOo + dd) * KT + t];
}

// ---------------------------------------------------------------- conv
// One block per (n, ci, co, spatial-tile of 768). Each thread: 3 positions,
// 16 Do accumulators. Weights are wave-uniform loads (SGPR path).
__global__ __launch_bounds__(256) void conv_uhat_k(const float* __restrict__ up,
                                                   const float* __restrict__ wT,
                                                   float* __restrict__ uhat) {
  const int blk  = blockIdx.x;
  const int tile = blk % 3;
  const int co   = (blk / 3) % COo;
  const int ci   = (blk / (3 * COo)) % CIc;
  const int n    = blk / (3 * COo * CIc);
  const int tid  = threadIdx.x;

  float acc[3][DOo];
#pragma unroll
  for (int j = 0; j < 3; ++j)
#pragma unroll
    for (int d = 0; d < DOo; ++d) acc[j][d] = 0.f;

  int hh[3], wwv[3];
#pragma unroll
  for (int j = 0; j < 3; ++j) {
    int p = tile * 768 + j * 256 + tid;
    hh[j]  = p / Ww;
    wwv[j] = p % Ww;
  }
  const float* upb   = up + (size_t)(n * CIc + ci) * DIc * (HP * WP);
  const float* wbase = wT + (size_t)(ci * COo + co) * KT * DOo;

  for (int di = 0; di < DIc; ++di) {
    const float* uplane = upb + di * (HP * WP);
#pragma unroll
    for (int kh = 0; kh < 5; ++kh) {
      const float* wrow0 = wbase + (di * 25 + kh * 5) * DOo;
      const float* urow0 = uplane + kh * WP;
#pragma unroll
      for (int kw = 0; kw < 5; ++kw) {
        const float* wr = wrow0 + kw * DOo;
        float uv[3];
#pragma unroll
        for (int j = 0; j < 3; ++j)
          uv[j] = urow0[hh[j] * WP + wwv[j] + kw];
#pragma unroll
        for (int d = 0; d < DOo; ++d) {
          float wv = wr[d];
#pragma unroll
          for (int j = 0; j < 3; ++j)
            acc[j][d] = fmaf(uv[j], wv, acc[j][d]);
        }
      }
    }
  }
  float* ob = uhat + (size_t)((n * CIc + ci) * COo + co) * DOo * HW +
              tile * 768 + tid;
#pragma unroll
  for (int d = 0; d < DOo; ++d)
#pragma unroll
    for (int j = 0; j < 3; ++j)
      ob[(size_t)d * HW + j * 256] = acc[j][d];
}

// ----------------------------------------------------- routing stats (R1)
// One block per (n,ci). Computes bmax = maxpool5x5(max_co b) and
// isum = 1 / boxfilter5x5(sum_co exp(b - bmax)).
__global__ __launch_bounds__(256) void routing_stats_k(const float* __restrict__ b,
                                                       float* __restrict__ bmax,
                                                       float* __restrict__ isum,
                                                       int zb) {
  __shared__ float m_lds[HW];
  __shared__ float cs_lds[HW];
  const int blk = blockIdx.x;   // n*CIc + ci
  const int tid = threadIdx.x;
  const float* bp = b + (size_t)blk * COo * HW;

  for (int p = tid; p < HW; p += 256) {
    float m;
    if (zb) {
      m = 0.f;
    } else {
      m = -INFINITY;
      for (int co = 0; co < COo; ++co) m = fmaxf(m, bp[(size_t)co * HW + p]);
    }
    m_lds[p] = m;
  }
  __syncthreads();

  for (int p = tid; p < HW; p += 256) {
    int h = p / Ww, w = p % Ww;
    float bm = -INFINITY;
    for (int kh = -2; kh <= 2; ++kh) {
      int hh = h + kh;
      if (hh < 0 || hh >= Hh) continue;
      for (int kw = -2; kw <= 2; ++kw) {
        int ww2 = w + kw;
        if (ww2 < 0 || ww2 >= Ww) continue;
        bm = fmaxf(bm, m_lds[hh * Ww + ww2]);
      }
    }
    bmax[(size_t)blk * HW + p] = bm;
    float cs;
    if (zb) {
      cs = 16.f;   // b==0 -> bm==0 -> sum_co exp(0)=16
    } else {
      cs = 0.f;
      for (int co = 0; co < COo; ++co)
        cs += __expf(bp[(size_t)co * HW + p] - bm);
    }
    cs_lds[p] = cs;
  }
  __syncthreads();

  for (int p = tid; p < HW; p += 256) {
    int h = p / Ww, w = p % Ww;
    float s = 0.f;
    for (int kh = -2; kh <= 2; ++kh) {
      int hh = h + kh;
      if (hh < 0 || hh >= Hh) continue;
      for (int kw = -2; kw <= 2; ++kw) {
        int ww2 = w + kw;
        if (ww2 < 0 || ww2 >= Ww) continue;
        s += cs_lds[hh * Ww + ww2];
      }
    }
    isum[(size_t)blk * HW + p] = 1.f / s;
  }
}

// -------------------------------------------------------- p + squash (R2)
// One thread per (n, co, p). r recomputed on the fly.
__global__ __launch_bounds__(256) void compute_v_k(const float* __restrict__ b,
                                                   const float* __restrict__ bmax,
                                                   const float* __restrict__ isum,
                                                   const float* __restrict__ uhat,
                                                   float* __restrict__ v,
                                                   int zb) {
  int idx = blockIdx.x * 256 + threadIdx.x;   // (n*COo+co)*HW + p
  int p  = idx % HW;
  int t  = idx / HW;
  int co = t % COo;
  int n  = t / COo;

  float acc[DOo];
#pragma unroll
  for (int d = 0; d < DOo; ++d) acc[d] = 0.f;

  for (int ci = 0; ci < CIc; ++ci) {
    float bl = zb ? 0.f : b[(size_t)((n * CIc + ci) * COo + co) * HW + p];
    float r  = __expf(bl - bmax[(size_t)(n * CIc + ci) * HW + p]) *
               isum[(size_t)(n * CIc + ci) * HW + p];
    const float* uh = uhat + (size_t)((n * CIc + ci) * COo + co) * DOo * HW + p;
#pragma unroll
    for (int d = 0; d < DOo; ++d)
      acc[d] = fmaf(r, uh[(size_t)d * HW], acc[d]);
  }
  float nsq = 0.f;
#pragma unroll
  for (int d = 0; d < DOo; ++d) nsq += acc[d] * acc[d];
  float scale = nsq / (1.f + nsq) / sqrtf(nsq + 1e-9f);

  float* vp = v + (size_t)(n * COo + co) * DOo * HW + p;
#pragma unroll
  for (int d = 0; d < DOo; ++d) vp[(size_t)d * HW] = acc[d] * scale;
}

// ---------------------------------------------------------- b update (R3)
__global__ __launch_bounds__(256) void update_b_k(const float* __restrict__ uhat,
                                                  const float* __restrict__ v,
                                                  float* __restrict__ b,
                                                  int zb) {
  int idx = blockIdx.x * 256 + threadIdx.x;   // ((n*CIc+ci)*COo+co)*HW + p
  int p  = idx % HW;
  int t  = idx / HW;
  int co = t % COo;
  t /= COo;
  int ci = t % CIc;
  int n  = t / CIc;

  const float* uh = uhat + (size_t)((n * CIc + ci) * COo + co) * DOo * HW + p;
  const float* vp = v + (size_t)(n * COo + co) * DOo * HW + p;
  float dot = 0.f;
#pragma unroll
  for (int d = 0; d < DOo; ++d)
    dot = fmaf(uh[(size_t)d * HW], vp[(size_t)d * HW], dot);
  b[idx] = (zb ? 0.f : b[idx]) + dot;
}

// ------------------------------------------------------------------ launch
extern "C" void kernel_launch(void* const* d_in, const int* in_sizes, int n_in,
                              void* d_out, int out_size, void* d_ws, size_t ws_size,
                              hipStream_t stream) {
  const float* u = (const float*)d_in[0];
  const float* w = (const float*)d_in[1];
  float* out = (float*)d_out;
  float* ws  = (float*)d_ws;

  float* up   = ws + OFF_UP;
  float* wT   = ws + OFF_WT;
  float* uhat = ws + OFF_UH;
  float* b    = ws + OFF_B;
  float* bm   = ws + OFF_BM;
  float* is   = ws + OFF_IS;
  float* v    = ws + OFF_V;

  pad_u_k<<<(SZ_UP + 255) / 256, 256, 0, stream>>>(u, up);
  transpose_w_k<<<(SZ_WT + 255) / 256, 256, 0, stream>>>(w, wT);
  conv_uhat_k<<<NN * CIc * COo * 3, 256, 0, stream>>>(up, wT, uhat);

  // routing d = 0 (b == 0 implicit)
  routing_stats_k<<<NN * CIc, 256, 0, stream>>>(b, bm, is, 1);
  compute_v_k<<<(NN * COo * HW) / 256, 256, 0, stream>>>(b, bm, is, uhat, v, 1);
  update_b_k<<<(SZ_B) / 256, 256, 0, stream>>>(uhat, v, b, 1);

  // routing d = 1
  routing_stats_k<<<NN * CIc, 256, 0, stream>>>(b, bm, is, 0);
  compute_v_k<<<(NN * COo * HW) / 256, 256, 0, stream>>>(b, bm, is, uhat, v, 0);
  update_b_k<<<(SZ_B) / 256, 256, 0, stream>>>(uhat, v, b, 0);

  // routing d = 2 -> final v straight to d_out
  routing_stats_k<<<NN * CIc, 256, 0, stream>>>(b, bm, is, 0);
  compute_v_k<<<(NN * COo * HW) / 256, 256, 0, stream>>>(b, bm, is, uhat, out, 0);
}

// Round 2
// 349.811 us; speedup vs baseline: 1.0933x; 1.0933x over previous
//
#include <hip/hip_runtime.h>
#include <math.h>

// Problem constants
#define NN  8
#define CIc 8
#define DIc 8
#define Hh  48
#define Ww  48
#define COo 16
#define DOo 16
#define HW  2304      // 48*48
#define HP  52
#define WP  52
#define KT  200       // DIc*5*5
#define PLANE (HP*WP) // 2704

// Workspace layout (float offsets). Total ~42.2M floats = ~169 MB.
#define OFF_UP   0
#define SZ_UP    (NN*CIc*DIc*PLANE)          // 1,384,448
#define OFF_WT   (OFF_UP + SZ_UP)
#define SZ_WT    (CIc*COo*KT*DOo)            // 409,600
#define OFF_UH   (OFF_WT + SZ_WT)
#define SZ_UH    (NN*CIc*COo*HW*DOo)         // 37,748,736  layout [n,ci,co,p,do]
#define OFF_B    (OFF_UH + SZ_UH)
#define SZ_B     (NN*CIc*COo*HW)             // 2,359,296
#define OFF_BM   (OFF_B + SZ_B)
#define SZ_BM    (NN*CIc*HW)                 // 147,456
#define OFF_IS   (OFF_BM + SZ_BM)
#define SZ_IS    (NN*CIc*HW)

// ---------------------------------------------------------------- pad u
__global__ __launch_bounds__(256) void pad_u_k(const float* __restrict__ u,
                                               float* __restrict__ up) {
  int idx = blockIdx.x * 256 + threadIdx.x;
  if (idx >= SZ_UP) return;
  int pw = idx % WP;
  int t  = idx / WP;
  int ph = t % HP;
  t /= HP;                       // t = (n*CIc+ci)*DIc+di
  int h = ph - 2, w = pw - 2;
  float val = 0.f;
  if (h >= 0 && h < Hh && w >= 0 && w < Ww)
    val = u[(size_t)t * (Hh * Ww) + h * Ww + w];
  up[idx] = val;
}

// ------------------------------------------------------------ transpose w
// wT[(ci*COo+co)*KT + t][do] = w[(ci*256 + co*16 + do)*KT + t]
__global__ __launch_bounds__(256) void transpose_w_k(const float* __restrict__ w,
                                                     float* __restrict__ wT) {
  int idx = blockIdx.x * 256 + threadIdx.x;
  if (idx >= SZ_WT) return;
  int dd = idx % DOo;
  int t2 = idx / DOo;
  int t  = t2 % KT;
  t2 /= KT;
  int co = t2 % COo;
  int ci = t2 / COo;
  wT[idx] = w[(size_t)(ci * (COo * DOo) + co * DOo + dd) * KT + t];
}

// ---------------------------------------------------------------- conv
// One block per (n, ci, co, tile of 256 positions). One position per thread,
// 16 Do accumulators. Weights are wave-uniform loads (SGPR path).
// Output layout: uhat[n][ci][co][p][do]  (do innermost for float4 I/O).
__global__ __launch_bounds__(256) void conv_uhat_k(const float* __restrict__ up,
                                                   const float* __restrict__ wT,
                                                   float* __restrict__ uhat) {
  const int blk  = blockIdx.x;
  const int tile = blk % 9;
  const int co   = (blk / 9) % COo;
  const int ci   = (blk / (9 * COo)) % CIc;
  const int n    = blk / (9 * COo * CIc);
  const int p    = tile * 256 + threadIdx.x;
  const int h    = p / Ww, w = p % Ww;

  float acc[DOo];
#pragma unroll
  for (int d = 0; d < DOo; ++d) acc[d] = 0.f;

  const float* upb = up + (size_t)(n * CIc + ci) * DIc * PLANE + h * WP + w;
  const float* wb  = wT + (size_t)(ci * COo + co) * KT * DOo;

  for (int di = 0; di < DIc; ++di) {
    const float* uplane = upb + di * PLANE;
    const float* wdi    = wb + di * 25 * DOo;
#pragma unroll
    for (int kh = 0; kh < 5; ++kh) {
#pragma unroll
      for (int kw = 0; kw < 5; ++kw) {
        float uv = uplane[kh * WP + kw];
        const float* wr = wdi + (kh * 5 + kw) * DOo;
#pragma unroll
        for (int d = 0; d < DOo; ++d) acc[d] = fmaf(uv, wr[d], acc[d]);
      }
    }
  }
  float4* ob = (float4*)(uhat + ((size_t)((n * CIc + ci) * COo + co) * HW + p) * DOo);
  ob[0] = make_float4(acc[0],  acc[1],  acc[2],  acc[3]);
  ob[1] = make_float4(acc[4],  acc[5],  acc[6],  acc[7]);
  ob[2] = make_float4(acc[8],  acc[9],  acc[10], acc[11]);
  ob[3] = make_float4(acc[12], acc[13], acc[14], acc[15]);
}

// ----------------------------------------------------- routing stats
// One block per (n,ci). bmax = maxpool5x5(max_co b); isum = 1/boxfilter5x5(sum_co exp(b-bmax)).
__global__ __launch_bounds__(256) void routing_stats_k(const float* __restrict__ b,
                                                       float* __restrict__ bmax,
                                                       float* __restrict__ isum,
                                                       int zb) {
  __shared__ float m_lds[HW];
  __shared__ float cs_lds[HW];
  const int blk = blockIdx.x;   // n*CIc + ci
  const int tid = threadIdx.x;
  const float* bp = b + (size_t)blk * COo * HW;

  for (int p = tid; p < HW; p += 256) {
    float m;
    if (zb) {
      m = 0.f;
    } else {
      m = -INFINITY;
      for (int co = 0; co < COo; ++co) m = fmaxf(m, bp[(size_t)co * HW + p]);
    }
    m_lds[p] = m;
  }
  __syncthreads();

  for (int p = tid; p < HW; p += 256) {
    int h = p / Ww, w = p % Ww;
    float bm = -INFINITY;
    for (int kh = -2; kh <= 2; ++kh) {
      int hh = h + kh;
      if (hh < 0 || hh >= Hh) continue;
      for (int kw = -2; kw <= 2; ++kw) {
        int ww2 = w + kw;
        if (ww2 < 0 || ww2 >= Ww) continue;
        bm = fmaxf(bm, m_lds[hh * Ww + ww2]);
      }
    }
    bmax[(size_t)blk * HW + p] = bm;
    float cs;
    if (zb) {
      cs = 16.f;   // b==0 -> bm==0 -> sum_co exp(0)=16
    } else {
      cs = 0.f;
      for (int co = 0; co < COo; ++co)
        cs += __expf(bp[(size_t)co * HW + p] - bm);
    }
    cs_lds[p] = cs;
  }
  __syncthreads();

  for (int p = tid; p < HW; p += 256) {
    int h = p / Ww, w = p % Ww;
    float s = 0.f;
    for (int kh = -2; kh <= 2; ++kh) {
      int hh = h + kh;
      if (hh < 0 || hh >= Hh) continue;
      for (int kw = -2; kw <= 2; ++kw) {
        int ww2 = w + kw;
        if (ww2 < 0 || ww2 >= Ww) continue;
        s += cs_lds[hh * Ww + ww2];
      }
    }
    isum[(size_t)blk * HW + p] = 1.f / s;
  }
}

// ------------------------------------------- fused p + squash + b-update
// One thread per (n, co, p). u_hat (8 ci x 16 do) held in registers; read ONCE.
// If last: write v to vout ([n,co,do,p]); else: b += uh . v, write bout.
__global__ __launch_bounds__(256, 2) void fused_route_k(const float* __restrict__ b,
                                                        const float* __restrict__ bmax,
                                                        const float* __restrict__ isum,
                                                        const float* __restrict__ uhat,
                                                        float* __restrict__ bout,
                                                        float* __restrict__ vout,
                                                        int zb, int last) {
  int idx = blockIdx.x * 256 + threadIdx.x;   // (n*COo+co)*HW + p
  int p  = idx % HW;
  int t  = idx / HW;
  int co = t % COo;
  int n  = t / COo;

  float bl[CIc], r[CIc];
#pragma unroll
  for (int ci = 0; ci < CIc; ++ci) {
    int s = n * CIc + ci;
    bl[ci] = zb ? 0.f : b[(size_t)(s * COo + co) * HW + p];
    r[ci]  = __expf(bl[ci] - bmax[(size_t)s * HW + p]) * isum[(size_t)s * HW + p];
  }

  float4 uh[CIc][4];
  float4 a0 = make_float4(0.f, 0.f, 0.f, 0.f);
  float4 a1 = a0, a2 = a0, a3 = a0;
#pragma unroll
  for (int ci = 0; ci < CIc; ++ci) {
    const float4* uhp = (const float4*)(uhat +
        ((size_t)((n * CIc + ci) * COo + co) * HW + p) * DOo);
#pragma unroll
    for (int k = 0; k < 4; ++k) uh[ci][k] = uhp[k];
    float rc = r[ci];
    a0.x = fmaf(rc, uh[ci][0].x, a0.x); a0.y = fmaf(rc, uh[ci][0].y, a0.y);
    a0.z = fmaf(rc, uh[ci][0].z, a0.z); a0.w = fmaf(rc, uh[ci][0].w, a0.w);
    a1.x = fmaf(rc, uh[ci][1].x, a1.x); a1.y = fmaf(rc, uh[ci][1].y, a1.y);
    a1.z = fmaf(rc, uh[ci][1].z, a1.z); a1.w = fmaf(rc, uh[ci][1].w, a1.w);
    a2.x = fmaf(rc, uh[ci][2].x, a2.x); a2.y = fmaf(rc, uh[ci][2].y, a2.y);
    a2.z = fmaf(rc, uh[ci][2].z, a2.z); a2.w = fmaf(rc, uh[ci][2].w, a2.w);
    a3.x = fmaf(rc, uh[ci][3].x, a3.x); a3.y = fmaf(rc, uh[ci][3].y, a3.y);
    a3.z = fmaf(rc, uh[ci][3].z, a3.z); a3.w = fmaf(rc, uh[ci][3].w, a3.w);
  }

  float nsq = a0.x*a0.x + a0.y*a0.y + a0.z*a0.z + a0.w*a0.w
            + a1.x*a1.x + a1.y*a1.y + a1.z*a1.z + a1.w*a1.w
            + a2.x*a2.x + a2.y*a2.y + a2.z*a2.z + a2.w*a2.w
            + a3.x*a3.x + a3.y*a3.y + a3.z*a3.z + a3.w*a3.w;
  float scale = nsq / (1.f + nsq) / sqrtf(nsq + 1e-9f);
  a0.x *= scale; a0.y *= scale; a0.z *= scale; a0.w *= scale;
  a1.x *= scale; a1.y *= scale; a1.z *= scale; a1.w *= scale;
  a2.x *= scale; a2.y *= scale; a2.z *= scale; a2.w *= scale;
  a3.x *= scale; a3.y *= scale; a3.z *= scale; a3.w *= scale;

  if (last) {
    float* vp = vout + (size_t)(n * COo + co) * DOo * HW + p;
    vp[0*HW]=a0.x; vp[1*HW]=a0.y; vp[2*HW]=a0.z; vp[3*HW]=a0.w;
    vp[4*HW]=a1.x; vp[5*HW]=a1.y; vp[6*HW]=a1.z; vp[7*HW]=a1.w;
    vp[8*HW]=a2.x; vp[9*HW]=a2.y; vp[10*HW]=a2.z; vp[11*HW]=a2.w;
    vp[12*HW]=a3.x; vp[13*HW]=a3.y; vp[14*HW]=a3.z; vp[15*HW]=a3.w;
  } else {
#pragma unroll
    for (int ci = 0; ci < CIc; ++ci) {
      float dot = uh[ci][0].x*a0.x + uh[ci][0].y*a0.y + uh[ci][0].z*a0.z + uh[ci][0].w*a0.w
                + uh[ci][1].x*a1.x + uh[ci][1].y*a1.y + uh[ci][1].z*a1.z + uh[ci][1].w*a1.w
                + uh[ci][2].x*a2.x + uh[ci][2].y*a2.y + uh[ci][2].z*a2.z + uh[ci][2].w*a2.w
                + uh[ci][3].x*a3.x + uh[ci][3].y*a3.y + uh[ci][3].z*a3.z + uh[ci][3].w*a3.w;
      bout[(size_t)((n * CIc + ci) * COo + co) * HW + p] = bl[ci] + dot;
    }
  }
}

// ------------------------------------------------------------------ launch
extern "C" void kernel_launch(void* const* d_in, const int* in_sizes, int n_in,
                              void* d_out, int out_size, void* d_ws, size_t ws_size,
                              hipStream_t stream) {
  const float* u = (const float*)d_in[0];
  const float* w = (const float*)d_in[1];
  float* out = (float*)d_out;
  float* ws  = (float*)d_ws;

  float* up   = ws + OFF_UP;
  float* wT   = ws + OFF_WT;
  float* uhat = ws + OFF_UH;
  float* b    = ws + OFF_B;
  float* bm   = ws + OFF_BM;
  float* is   = ws + OFF_IS;

  pad_u_k<<<(SZ_UP + 255) / 256, 256, 0, stream>>>(u, up);
  transpose_w_k<<<(SZ_WT + 255) / 256, 256, 0, stream>>>(w, wT);
  conv_uhat_k<<<NN * CIc * COo * 9, 256, 0, stream>>>(up, wT, uhat);

  const int route_grid = (NN * COo * HW) / 256;   // 1152

  // d = 0 (b == 0 implicit)
  routing_stats_k<<<NN * CIc, 256, 0, stream>>>(b, bm, is, 1);
  fused_route_k<<<route_grid, 256, 0, stream>>>(b, bm, is, uhat, b, out, 1, 0);

  // d = 1
  routing_stats_k<<<NN * CIc, 256, 0, stream>>>(b, bm, is, 0);
  fused_route_k<<<route_grid, 256, 0, stream>>>(b, bm, is, uhat, b, out, 0, 0);

  // d = 2 -> final v straight to d_out
  routing_stats_k<<<NN * CIc, 256, 0, stream>>>(b, bm, is, 0);
  fused_route_k<<<route_grid, 256, 0, stream>>>(b, bm, is, uhat, b, out, 0, 1);
}

// Round 3
// 224.153 us; speedup vs baseline: 1.7062x; 1.5606x over previous
//
#include <hip/hip_runtime.h>
#include <math.h>

// Problem constants
#define NN  8
#define CIc 8
#define DIc 8
#define Hh  48
#define Ww  48
#define COo 16
#define DOo 16
#define HW  2304      // 48*48
#define KSTR 232      // LDS k-stride for weights (odd # of 16B slots -> bank spread)

typedef _Float16 f16x8 __attribute__((ext_vector_type(8)));
typedef float f32x4 __attribute__((ext_vector_type(4)));

// ---------------- workspace layout (byte offsets) ----------------
// uhat : 37,748,736 f32  = 150,994,944 B   [n,ci,co,p,do]
// b    :  2,359,296 f32  =   9,437,184 B
// bm   :    147,456 f32  =     589,824 B
// is   :    147,456 f32  =     589,824 B
// uphi :  1,384,448 f16  =   2,768,896 B   [n,ci,row52,col52,di]
// uplo :  1,384,448 f16  =   2,768,896 B
// whi  :    458,752 f16  =     917,504 B   [ci,co,do,k224]  k = tap*8+di
// wlo  :    458,752 f16  =     917,504 B
#define OFFB_UHAT 0
#define OFFB_B    150994944
#define OFFB_BM   160432128
#define OFFB_IS   161021952
#define OFFB_UPHI 161611776
#define OFFB_UPLO 164380672
#define OFFB_WHI  167149568
#define OFFB_WLO  168067072

// ---------------------------------------------------- prep u (pad + fp16 split)
// One thread per (n,ci,row,col) of the 52x52 padded plane; handles 8 di.
// Output layout di-innermost so one B-fragment = one 16B LDS read later.
__global__ __launch_bounds__(256) void prep_u_k(const float* __restrict__ u,
                                                _Float16* __restrict__ uphi,
                                                _Float16* __restrict__ uplo) {
  int idx = blockIdx.x * 256 + threadIdx.x;
  if (idx >= NN * CIc * 52 * 52) return;
  int col = idx % 52;
  int t = idx / 52;
  int row = t % 52;
  t /= 52;                        // t = n*CIc + ci
  int h = row - 2, w = col - 2;
  f16x8 hv, lv;
#pragma unroll
  for (int di = 0; di < 8; ++di) {
    float val = 0.f;
    if (h >= 0 && h < Hh && w >= 0 && w < Ww)
      val = u[((size_t)t * DIc + di) * HW + h * Ww + w];
    _Float16 vh = (_Float16)val;
    float resid = (val - (float)vh) * 2048.0f;   // scale by 2^11: avoid subnormals
    hv[di] = vh;
    lv[di] = (_Float16)resid;
  }
  *(f16x8*)(uphi + (size_t)idx * 8) = hv;
  *(f16x8*)(uplo + (size_t)idx * 8) = lv;
}

// ---------------------------------------------------- prep w (reorder + split)
// One thread per (ci,co,do,tap); tap in 0..27 (25 real + 3 zero-pad). 8 di each.
// Output [ci][co][do][k=tap*8+di].
__global__ __launch_bounds__(256) void prep_w_k(const float* __restrict__ w,
                                                _Float16* __restrict__ whi,
                                                _Float16* __restrict__ wlo) {
  int idx = blockIdx.x * 256 + threadIdx.x;
  if (idx >= CIc * COo * DOo * 28) return;
  int tap = idx % 28;
  int t = idx / 28;
  int dd = t % DOo;
  t /= DOo;
  int co = t % COo;
  int ci = t / COo;
  f16x8 hv, lv;
#pragma unroll
  for (int di = 0; di < 8; ++di) {
    float val = 0.f;
    if (tap < 25)
      val = w[((size_t)(ci * 256 + co * 16 + dd)) * 200 + di * 25 + tap];
    _Float16 vh = (_Float16)val;
    float resid = (val - (float)vh) * 2048.0f;
    hv[di] = vh;
    lv[di] = (_Float16)resid;
  }
  size_t off = ((size_t)(ci * COo + co) * DOo + dd) * 224 + tap * 8;
  *(f16x8*)(whi + off) = hv;
  *(f16x8*)(wlo + off) = lv;
}

// ---------------------------------------------------------------- MFMA conv
// Per (n,ci): C[256 (co,do), 2304 (p)] = W[256, K224] x im2col(u)[K224, 2304]
// fp16x3 split: C = Whi*Xhi + 2^-11 * (Whi*Xlo' + Wlo'*Xhi)
// One block per (n, ci, co-quad). 4 waves; wave = one co. K-order: k=tap*8+di.
__global__ __launch_bounds__(256) void conv_mfma_k(const _Float16* __restrict__ uphi,
                                                   const _Float16* __restrict__ uplo,
                                                   const _Float16* __restrict__ whi,
                                                   const _Float16* __restrict__ wlo,
                                                   float* __restrict__ uhat) {
  __shared__ _Float16 s_uhi[53 * 52 * 8];   // 44,096 B (row 52 = zeros for pad taps)
  __shared__ _Float16 s_ulo[53 * 52 * 8];   // 44,096 B
  __shared__ _Float16 s_whi[64 * KSTR];     // 29,696 B
  __shared__ _Float16 s_wlo[64 * KSTR];     // 29,696 B   total 147,584 B

  const int blk = blockIdx.x;
  const int mq = blk & 3;
  const int ci = (blk >> 2) & 7;
  const int n  = blk >> 5;
  const int tid = threadIdx.x;

  // ---- stage u planes (hi+lo), linear copy, 2704 16B-slots each
  const _Float16* gu_hi = uphi + (size_t)(n * CIc + ci) * (52 * 52 * 8);
  const _Float16* gu_lo = uplo + (size_t)(n * CIc + ci) * (52 * 52 * 8);
  for (int it = tid; it < 2704; it += 256) {
    *(f16x8*)(s_uhi + it * 8) = *(const f16x8*)(gu_hi + it * 8);
    *(f16x8*)(s_ulo + it * 8) = *(const f16x8*)(gu_lo + it * 8);
  }
  {
    f16x8 z = {0, 0, 0, 0, 0, 0, 0, 0};
    for (int it = tid; it < 52; it += 256) {       // zero row 52
      *(f16x8*)(s_uhi + (52 * 52 + it) * 8) = z;
      *(f16x8*)(s_ulo + (52 * 52 + it) * 8) = z;
    }
  }
  // ---- stage weights for 4 co's: 64 rows x 28 slots -> stride KSTR
  const _Float16* gw_hi = whi + (size_t)(ci * COo + mq * 4) * DOo * 224;
  const _Float16* gw_lo = wlo + (size_t)(ci * COo + mq * 4) * DOo * 224;
  for (int it = tid; it < 1792; it += 256) {
    int r = it / 28, ks = it % 28;
    *(f16x8*)(s_whi + r * KSTR + ks * 8) = *(const f16x8*)(gw_hi + r * 224 + ks * 8);
    *(f16x8*)(s_wlo + r * KSTR + ks * 8) = *(const f16x8*)(gw_lo + r * 224 + ks * 8);
  }
  __syncthreads();

  const int wv = tid >> 6, lane = tid & 63;
  const int l15 = lane & 15, l4 = lane >> 4;
  const int a_off = (wv * 16 + l15) * KSTR + l4 * 8;
  const int co = mq * 4 + wv;
  float* ob = uhat + (size_t)((n * CIc + ci) * COo + co) * HW * 16;

  for (int chunk = 0; chunk < 36; ++chunk) {
    const int p0c = chunk * 64;
    f32x4 accH[4], accL[4];
#pragma unroll
    for (int nt = 0; nt < 4; ++nt) {
      f32x4 z = {0.f, 0.f, 0.f, 0.f};
      accH[nt] = z; accL[nt] = z;
    }
#pragma unroll
    for (int kstep = 0; kstep < 7; ++kstep) {
      f16x8 ahi = *(const f16x8*)(s_whi + a_off + kstep * 32);
      f16x8 alo = *(const f16x8*)(s_wlo + a_off + kstep * 32);
      const int tap = kstep * 4 + l4;      // 0..27
      const int dy = tap / 5;              // 0..5 (5 => zero row 52)
      const int dx = tap - dy * 5;
      const int b_woff = (dy * 52 + dx) * 8;
#pragma unroll
      for (int nt = 0; nt < 4; ++nt) {
        const int p0 = p0c + nt * 16;      // 16-run always within one row (48%16==0)
        const int prow = p0 / 48;
        const int pcol = p0 - prow * 48;
        const int slot = (prow * 52 + pcol + l15) * 8 + b_woff;
        f16x8 bhi = *(const f16x8*)(s_uhi + slot);
        f16x8 blo = *(const f16x8*)(s_ulo + slot);
        accH[nt] = __builtin_amdgcn_mfma_f32_16x16x32_f16(ahi, bhi, accH[nt], 0, 0, 0);
        accL[nt] = __builtin_amdgcn_mfma_f32_16x16x32_f16(ahi, blo, accL[nt], 0, 0, 0);
        accL[nt] = __builtin_amdgcn_mfma_f32_16x16x32_f16(alo, bhi, accL[nt], 0, 0, 0);
      }
    }
    // C fragment: col = lane&15 = position, row = (lane>>4)*4+j = do  -> float4 store
#pragma unroll
    for (int nt = 0; nt < 4; ++nt) {
      int p = p0c + nt * 16 + l15;
      f32x4 v = accH[nt] + accL[nt] * (1.0f / 2048.0f);
      *(f32x4*)(ob + (size_t)p * 16 + l4 * 4) = v;
    }
  }
}

// ----------------------------------------------------- routing stats
// One block per (n,ci). bmax = maxpool5x5(max_co b); isum = 1/boxfilter5x5(sum_co exp(b-bmax)).
__global__ __launch_bounds__(256) void routing_stats_k(const float* __restrict__ b,
                                                       float* __restrict__ bmax,
                                                       float* __restrict__ isum,
                                                       int zb) {
  __shared__ float m_lds[HW];
  __shared__ float cs_lds[HW];
  const int blk = blockIdx.x;   // n*CIc + ci
  const int tid = threadIdx.x;
  const float* bp = b + (size_t)blk * COo * HW;

  for (int p = tid; p < HW; p += 256) {
    float m;
    if (zb) {
      m = 0.f;
    } else {
      m = -INFINITY;
      for (int co = 0; co < COo; ++co) m = fmaxf(m, bp[(size_t)co * HW + p]);
    }
    m_lds[p] = m;
  }
  __syncthreads();

  for (int p = tid; p < HW; p += 256) {
    int h = p / Ww, w = p % Ww;
    float bm = -INFINITY;
    for (int kh = -2; kh <= 2; ++kh) {
      int hh = h + kh;
      if (hh < 0 || hh >= Hh) continue;
      for (int kw = -2; kw <= 2; ++kw) {
        int ww2 = w + kw;
        if (ww2 < 0 || ww2 >= Ww) continue;
        bm = fmaxf(bm, m_lds[hh * Ww + ww2]);
      }
    }
    bmax[(size_t)blk * HW + p] = bm;
    float cs;
    if (zb) {
      cs = 16.f;   // b==0 -> bm==0 -> sum_co exp(0)=16
    } else {
      cs = 0.f;
      for (int co = 0; co < COo; ++co)
        cs += __expf(bp[(size_t)co * HW + p] - bm);
    }
    cs_lds[p] = cs;
  }
  __syncthreads();

  for (int p = tid; p < HW; p += 256) {
    int h = p / Ww, w = p % Ww;
    float s = 0.f;
    for (int kh = -2; kh <= 2; ++kh) {
      int hh = h + kh;
      if (hh < 0 || hh >= Hh) continue;
      for (int kw = -2; kw <= 2; ++kw) {
        int ww2 = w + kw;
        if (ww2 < 0 || ww2 >= Ww) continue;
        s += cs_lds[hh * Ww + ww2];
      }
    }
    isum[(size_t)blk * HW + p] = 1.f / s;
  }
}

// ------------------------------------------- fused p + squash + b-update
// One thread per (n, co, p). u_hat (8 ci x 16 do) held in registers; read ONCE.
__global__ __launch_bounds__(256, 2) void fused_route_k(const float* __restrict__ b,
                                                        const float* __restrict__ bmax,
                                                        const float* __restrict__ isum,
                                                        const float* __restrict__ uhat,
                                                        float* __restrict__ bout,
                                                        float* __restrict__ vout,
                                                        int zb, int last) {
  int idx = blockIdx.x * 256 + threadIdx.x;   // (n*COo+co)*HW + p
  int p  = idx % HW;
  int t  = idx / HW;
  int co = t % COo;
  int n  = t / COo;

  float bl[CIc], r[CIc];
#pragma unroll
  for (int ci = 0; ci < CIc; ++ci) {
    int s = n * CIc + ci;
    bl[ci] = zb ? 0.f : b[(size_t)(s * COo + co) * HW + p];
    r[ci]  = __expf(bl[ci] - bmax[(size_t)s * HW + p]) * isum[(size_t)s * HW + p];
  }

  float4 uh[CIc][4];
  float4 a0 = make_float4(0.f, 0.f, 0.f, 0.f);
  float4 a1 = a0, a2 = a0, a3 = a0;
#pragma unroll
  for (int ci = 0; ci < CIc; ++ci) {
    const float4* uhp = (const float4*)(uhat +
        ((size_t)((n * CIc + ci) * COo + co) * HW + p) * DOo);
#pragma unroll
    for (int k = 0; k < 4; ++k) uh[ci][k] = uhp[k];
    float rc = r[ci];
    a0.x = fmaf(rc, uh[ci][0].x, a0.x); a0.y = fmaf(rc, uh[ci][0].y, a0.y);
    a0.z = fmaf(rc, uh[ci][0].z, a0.z); a0.w = fmaf(rc, uh[ci][0].w, a0.w);
    a1.x = fmaf(rc, uh[ci][1].x, a1.x); a1.y = fmaf(rc, uh[ci][1].y, a1.y);
    a1.z = fmaf(rc, uh[ci][1].z, a1.z); a1.w = fmaf(rc, uh[ci][1].w, a1.w);
    a2.x = fmaf(rc, uh[ci][2].x, a2.x); a2.y = fmaf(rc, uh[ci][2].y, a2.y);
    a2.z = fmaf(rc, uh[ci][2].z, a2.z); a2.w = fmaf(rc, uh[ci][2].w, a2.w);
    a3.x = fmaf(rc, uh[ci][3].x, a3.x); a3.y = fmaf(rc, uh[ci][3].y, a3.y);
    a3.z = fmaf(rc, uh[ci][3].z, a3.z); a3.w = fmaf(rc, uh[ci][3].w, a3.w);
  }

  float nsq = a0.x*a0.x + a0.y*a0.y + a0.z*a0.z + a0.w*a0.w
            + a1.x*a1.x + a1.y*a1.y + a1.z*a1.z + a1.w*a1.w
            + a2.x*a2.x + a2.y*a2.y + a2.z*a2.z + a2.w*a2.w
            + a3.x*a3.x + a3.y*a3.y + a3.z*a3.z + a3.w*a3.w;
  float scale = nsq / (1.f + nsq) / sqrtf(nsq + 1e-9f);
  a0.x *= scale; a0.y *= scale; a0.z *= scale; a0.w *= scale;
  a1.x *= scale; a1.y *= scale; a1.z *= scale; a1.w *= scale;
  a2.x *= scale; a2.y *= scale; a2.z *= scale; a2.w *= scale;
  a3.x *= scale; a3.y *= scale; a3.z *= scale; a3.w *= scale;

  if (last) {
    float* vp = vout + (size_t)(n * COo + co) * DOo * HW + p;
    vp[0*HW]=a0.x; vp[1*HW]=a0.y; vp[2*HW]=a0.z; vp[3*HW]=a0.w;
    vp[4*HW]=a1.x; vp[5*HW]=a1.y; vp[6*HW]=a1.z; vp[7*HW]=a1.w;
    vp[8*HW]=a2.x; vp[9*HW]=a2.y; vp[10*HW]=a2.z; vp[11*HW]=a2.w;
    vp[12*HW]=a3.x; vp[13*HW]=a3.y; vp[14*HW]=a3.z; vp[15*HW]=a3.w;
  } else {
#pragma unroll
    for (int ci = 0; ci < CIc; ++ci) {
      float dot = uh[ci][0].x*a0.x + uh[ci][0].y*a0.y + uh[ci][0].z*a0.z + uh[ci][0].w*a0.w
                + uh[ci][1].x*a1.x + uh[ci][1].y*a1.y + uh[ci][1].z*a1.z + uh[ci][1].w*a1.w
                + uh[ci][2].x*a2.x + uh[ci][2].y*a2.y + uh[ci][2].z*a2.z + uh[ci][2].w*a2.w
                + uh[ci][3].x*a3.x + uh[ci][3].y*a3.y + uh[ci][3].z*a3.z + uh[ci][3].w*a3.w;
      bout[(size_t)((n * CIc + ci) * COo + co) * HW + p] = bl[ci] + dot;
    }
  }
}

// ------------------------------------------------------------------ launch
extern "C" void kernel_launch(void* const* d_in, const int* in_sizes, int n_in,
                              void* d_out, int out_size, void* d_ws, size_t ws_size,
                              hipStream_t stream) {
  const float* u = (const float*)d_in[0];
  const float* w = (const float*)d_in[1];
  float* out = (float*)d_out;
  char* wsb  = (char*)d_ws;

  float*     uhat = (float*)(wsb + OFFB_UHAT);
  float*     b    = (float*)(wsb + OFFB_B);
  float*     bm   = (float*)(wsb + OFFB_BM);
  float*     is   = (float*)(wsb + OFFB_IS);
  _Float16*  uphi = (_Float16*)(wsb + OFFB_UPHI);
  _Float16*  uplo = (_Float16*)(wsb + OFFB_UPLO);
  _Float16*  whiT = (_Float16*)(wsb + OFFB_WHI);
  _Float16*  wloT = (_Float16*)(wsb + OFFB_WLO);

  prep_u_k<<<(NN * CIc * 52 * 52 + 255) / 256, 256, 0, stream>>>(u, uphi, uplo);
  prep_w_k<<<(CIc * COo * DOo * 28 + 255) / 256, 256, 0, stream>>>(w, whiT, wloT);
  conv_mfma_k<<<NN * CIc * 4, 256, 0, stream>>>(uphi, uplo, whiT, wloT, uhat);

  const int route_grid = (NN * COo * HW) / 256;   // 1152

  routing_stats_k<<<NN * CIc, 256, 0, stream>>>(b, bm, is, 1);
  fused_route_k<<<route_grid, 256, 0, stream>>>(b, bm, is, uhat, b, out, 1, 0);

  routing_stats_k<<<NN * CIc, 256, 0, stream>>>(b, bm, is, 0);
  fused_route_k<<<route_grid, 256, 0, stream>>>(b, bm, is, uhat, b, out, 0, 0);

  routing_stats_k<<<NN * CIc, 256, 0, stream>>>(b, bm, is, 0);
  fused_route_k<<<route_grid, 256, 0, stream>>>(b, bm, is, uhat, b, out, 0, 1);
}

// Round 4
// 157.425 us; speedup vs baseline: 2.4294x; 1.4239x over previous
//
#include <hip/hip_runtime.h>
#include <math.h>

// Problem constants
#define NN  8
#define CIc 8
#define DIc 8
#define Hh  48
#define Ww  48
#define COo 16
#define DOo 16
#define HW  2304      // 48*48

typedef _Float16 f16x8 __attribute__((ext_vector_type(8)));
typedef _Float16 f16x4 __attribute__((ext_vector_type(4)));
typedef float f32x4 __attribute__((ext_vector_type(4)));

// ---------------- workspace layout (byte offsets) ----------------
// uhat : 37,748,736 f16 =  75,497,472 B   [n,ci,co,p,do]
// b    :  2,359,296 f32 =   9,437,184 B
// bm   :    147,456 f32 =     589,824 B
// is   :    147,456 f32 =     589,824 B
// uphi :  1,384,448 f16 =   2,768,896 B   [n,ci,row52,col52,di]
// uplo :  1,384,448 f16 =   2,768,896 B
// whi  :    458,752 f16 =     917,504 B   [ci,co,do,k224]  k = tap*8+di
// wlo  :    458,752 f16 =     917,504 B
#define OFFB_UHAT 0
#define OFFB_B    75497472
#define OFFB_BM   84934656
#define OFFB_IS   85524480
#define OFFB_UPHI 86114304
#define OFFB_UPLO 88883200
#define OFFB_WHI  91652096
#define OFFB_WLO  92569600

// ---------------------------------------------------- prep u (pad + fp16 split)
__global__ __launch_bounds__(256) void prep_u_k(const float* __restrict__ u,
                                                _Float16* __restrict__ uphi,
                                                _Float16* __restrict__ uplo) {
  int idx = blockIdx.x * 256 + threadIdx.x;
  if (idx >= NN * CIc * 52 * 52) return;
  int col = idx % 52;
  int t = idx / 52;
  int row = t % 52;
  t /= 52;                        // t = n*CIc + ci
  int h = row - 2, w = col - 2;
  f16x8 hv, lv;
#pragma unroll
  for (int di = 0; di < 8; ++di) {
    float val = 0.f;
    if (h >= 0 && h < Hh && w >= 0 && w < Ww)
      val = u[((size_t)t * DIc + di) * HW + h * Ww + w];
    _Float16 vh = (_Float16)val;
    float resid = (val - (float)vh) * 2048.0f;   // 2^11 scale: dodge subnormals
    hv[di] = vh;
    lv[di] = (_Float16)resid;
  }
  *(f16x8*)(uphi + (size_t)idx * 8) = hv;
  *(f16x8*)(uplo + (size_t)idx * 8) = lv;
}

// ---------------------------------------------------- prep w (reorder + split)
// [ci][co][do][k=tap*8+di], taps 25..27 zero-padded.
__global__ __launch_bounds__(256) void prep_w_k(const float* __restrict__ w,
                                                _Float16* __restrict__ whi,
                                                _Float16* __restrict__ wlo) {
  int idx = blockIdx.x * 256 + threadIdx.x;
  if (idx >= CIc * COo * DOo * 28) return;
  int tap = idx % 28;
  int t = idx / 28;
  int dd = t % DOo;
  t /= DOo;
  int co = t % COo;
  int ci = t / COo;
  f16x8 hv, lv;
#pragma unroll
  for (int di = 0; di < 8; ++di) {
    float val = 0.f;
    if (tap < 25)
      val = w[((size_t)(ci * 256 + co * 16 + dd)) * 200 + di * 25 + tap];
    _Float16 vh = (_Float16)val;
    float resid = (val - (float)vh) * 2048.0f;
    hv[di] = vh;
    lv[di] = (_Float16)resid;
  }
  size_t off = ((size_t)(ci * COo + co) * DOo + dd) * 224 + tap * 8;
  *(f16x8*)(whi + off) = hv;
  *(f16x8*)(wlo + off) = lv;
}

// ---------------------------------------------------------------- MFMA conv
// Per (n,ci): C[256 (co,do), 2304 p] = W[256,224] x im2col(u)[224,2304], fp16x3.
// Block = (n, ci, co-half, row-half): 512 thr / 8 waves, wave = one co.
// Weights held in registers (per-wave A-fragments); LDS = u half-plane only.
__global__ __launch_bounds__(512, 2) void conv_mfma_k(const _Float16* __restrict__ uphi,
                                                      const _Float16* __restrict__ uplo,
                                                      const _Float16* __restrict__ whi,
                                                      const _Float16* __restrict__ wlo,
                                                      _Float16* __restrict__ uhat) {
  __shared__ _Float16 s_uhi[29 * 52 * 8];   // 24,128 B (row 28 = zeros)
  __shared__ _Float16 s_ulo[29 * 52 * 8];   // 24,128 B  -> 48,256 B total

  const int blk = blockIdx.x;
  const int ph  = blk & 1;          // row half: rows ph*24 .. ph*24+23
  const int coh = (blk >> 1) & 1;   // co half
  const int ci  = (blk >> 2) & 7;
  const int n   = blk >> 5;
  const int tid = threadIdx.x;

  const int wv = tid >> 6, lane = tid & 63;
  const int l15 = lane & 15, l4 = lane >> 4;
  const int co = coh * 8 + wv;

  // per-wave weight A-fragments -> registers (7 ksteps, hi+lo)
  const _Float16* wbh = whi + ((size_t)(ci * COo + co) * DOo + l15) * 224 + l4 * 8;
  const _Float16* wbl = wlo + ((size_t)(ci * COo + co) * DOo + l15) * 224 + l4 * 8;
  f16x8 ahi[7], alo[7];
#pragma unroll
  for (int ks = 0; ks < 7; ++ks) {
    ahi[ks] = *(const f16x8*)(wbh + ks * 32);
    alo[ks] = *(const f16x8*)(wbl + ks * 32);
  }

  // stage u half-plane: padded rows rb..rb+27, plus zero row 28
  const int rb = ph * 24;
  const _Float16* gu_hi = uphi + (size_t)(n * CIc + ci) * (52 * 52 * 8) + rb * 52 * 8;
  const _Float16* gu_lo = uplo + (size_t)(n * CIc + ci) * (52 * 52 * 8) + rb * 52 * 8;
  for (int it = tid; it < 28 * 52; it += 512) {
    *(f16x8*)(s_uhi + it * 8) = *(const f16x8*)(gu_hi + it * 8);
    *(f16x8*)(s_ulo + it * 8) = *(const f16x8*)(gu_lo + it * 8);
  }
  if (tid < 52) {
    f16x8 z = {0, 0, 0, 0, 0, 0, 0, 0};
    *(f16x8*)(s_uhi + (28 * 52 + tid) * 8) = z;
    *(f16x8*)(s_ulo + (28 * 52 + tid) * 8) = z;
  }
  __syncthreads();

  _Float16* ob = uhat + (size_t)((n * CIc + ci) * COo + co) * HW * 16;

  for (int chunk = 0; chunk < 18; ++chunk) {
    const int q0 = chunk * 64;           // local position within half (0..1151)
    f32x4 accH[4], accL[4];
#pragma unroll
    for (int nt = 0; nt < 4; ++nt) {
      f32x4 z = {0.f, 0.f, 0.f, 0.f};
      accH[nt] = z; accL[nt] = z;
    }
#pragma unroll
    for (int ks = 0; ks < 7; ++ks) {
      const int tap = ks * 4 + l4;       // 0..27 (25..27 hit zero row)
      const int dy = tap / 5;
      const int dx = tap - dy * 5;
      const int boff = (dy * 52 + dx) * 8;
#pragma unroll
      for (int nt = 0; nt < 4; ++nt) {
        const int q = q0 + nt * 16;      // 16-run within one row (48%16==0)
        const int prow = q / 48;
        const int pcol = q - prow * 48;
        const int slot = (prow * 52 + pcol + l15) * 8 + boff;
        f16x8 bhi = *(const f16x8*)(s_uhi + slot);
        f16x8 blo = *(const f16x8*)(s_ulo + slot);
        accH[nt] = __builtin_amdgcn_mfma_f32_16x16x32_f16(ahi[ks], bhi, accH[nt], 0, 0, 0);
        accL[nt] = __builtin_amdgcn_mfma_f32_16x16x32_f16(ahi[ks], blo, accL[nt], 0, 0, 0);
        accL[nt] = __builtin_amdgcn_mfma_f32_16x16x32_f16(alo[ks], bhi, accL[nt], 0, 0, 0);
      }
    }
    // C frag: col = l15 = position, row = l4*4+j = do  -> f16x4 store
#pragma unroll
    for (int nt = 0; nt < 4; ++nt) {
      int p = ph * 1152 + q0 + nt * 16 + l15;
      f32x4 vv = accH[nt] + accL[nt] * (1.0f / 2048.0f);
      f16x4 hv;
      hv[0] = (_Float16)vv[0]; hv[1] = (_Float16)vv[1];
      hv[2] = (_Float16)vv[2]; hv[3] = (_Float16)vv[3];
      *(f16x4*)(ob + (size_t)p * 16 + l4 * 4) = hv;
    }
  }
}

// ----------------------------------------------------- routing stats (separable)
// One block per (n,ci). bmax = maxpool5x5(max_co b); isum = 1/boxfilter5x5(sum_co exp(b-bmax)).
__global__ __launch_bounds__(256) void routing_stats_k(const float* __restrict__ b,
                                                       float* __restrict__ bmax,
                                                       float* __restrict__ isum,
                                                       int zb) {
  __shared__ float m_lds[HW];
  __shared__ float t_lds[HW];
  const int blk = blockIdx.x;   // n*CIc + ci
  const int tid = threadIdx.x;
  const float* bp = b + (size_t)blk * COo * HW;

  for (int p = tid; p < HW; p += 256) {
    float m;
    if (zb) {
      m = 0.f;
    } else {
      m = -INFINITY;
      for (int co = 0; co < COo; ++co) m = fmaxf(m, bp[(size_t)co * HW + p]);
    }
    m_lds[p] = m;
  }
  __syncthreads();
  // row-max
  for (int p = tid; p < HW; p += 256) {
    int h = p / Ww, w = p % Ww;
    float v = -INFINITY;
#pragma unroll
    for (int dx = -2; dx <= 2; ++dx) {
      int ww2 = w + dx;
      if (ww2 >= 0 && ww2 < Ww) v = fmaxf(v, m_lds[h * Ww + ww2]);
    }
    t_lds[p] = v;
  }
  __syncthreads();
  // col-max -> bmax; cs into m_lds
  for (int p = tid; p < HW; p += 256) {
    int h = p / Ww, w = p % Ww;
    float bm = -INFINITY;
#pragma unroll
    for (int dy = -2; dy <= 2; ++dy) {
      int hh = h + dy;
      if (hh >= 0 && hh < Hh) bm = fmaxf(bm, t_lds[hh * Ww + w]);
    }
    bmax[(size_t)blk * HW + p] = bm;
    float cs;
    if (zb) {
      cs = 16.f;
    } else {
      cs = 0.f;
      for (int co = 0; co < COo; ++co)
        cs += __expf(bp[(size_t)co * HW + p] - bm);
    }
    m_lds[p] = cs;
  }
  __syncthreads();
  // row-sum
  for (int p = tid; p < HW; p += 256) {
    int h = p / Ww, w = p % Ww;
    float s = 0.f;
#pragma unroll
    for (int dx = -2; dx <= 2; ++dx) {
      int ww2 = w + dx;
      if (ww2 >= 0 && ww2 < Ww) s += m_lds[h * Ww + ww2];
    }
    t_lds[p] = s;
  }
  __syncthreads();
  // col-sum -> isum
  for (int p = tid; p < HW; p += 256) {
    int h = p / Ww, w = p % Ww;
    float s = 0.f;
#pragma unroll
    for (int dy = -2; dy <= 2; ++dy) {
      int hh = h + dy;
      if (hh >= 0 && hh < Hh) s += t_lds[hh * Ww + w];
    }
    isum[(size_t)blk * HW + p] = 1.f / s;
  }
}

// ------------------------------------------- fused p + squash + b-update
// One thread per (n, co, p). u_hat (8 ci x 16 do, fp16) read ONCE into regs.
__global__ __launch_bounds__(256, 2) void fused_route_k(const float* __restrict__ b,
                                                        const float* __restrict__ bmax,
                                                        const float* __restrict__ isum,
                                                        const _Float16* __restrict__ uhat,
                                                        float* __restrict__ bout,
                                                        float* __restrict__ vout,
                                                        int zb, int last) {
  int idx = blockIdx.x * 256 + threadIdx.x;   // (n*COo+co)*HW + p
  int p  = idx % HW;
  int t  = idx / HW;
  int co = t % COo;
  int n  = t / COo;

  float bl[CIc], r[CIc];
#pragma unroll
  for (int ci = 0; ci < CIc; ++ci) {
    int s = n * CIc + ci;
    bl[ci] = zb ? 0.f : b[(size_t)(s * COo + co) * HW + p];
    r[ci]  = __expf(bl[ci] - bmax[(size_t)s * HW + p]) * isum[(size_t)s * HW + p];
  }

  float4 uh[CIc][4];
  float4 a0 = make_float4(0.f, 0.f, 0.f, 0.f);
  float4 a1 = a0, a2 = a0, a3 = a0;
#pragma unroll
  for (int ci = 0; ci < CIc; ++ci) {
    const f16x8* uhp = (const f16x8*)(uhat +
        ((size_t)((n * CIc + ci) * COo + co) * HW + p) * DOo);
    f16x8 h0 = uhp[0], h1 = uhp[1];
    uh[ci][0] = make_float4((float)h0[0], (float)h0[1], (float)h0[2], (float)h0[3]);
    uh[ci][1] = make_float4((float)h0[4], (float)h0[5], (float)h0[6], (float)h0[7]);
    uh[ci][2] = make_float4((float)h1[0], (float)h1[1], (float)h1[2], (float)h1[3]);
    uh[ci][3] = make_float4((float)h1[4], (float)h1[5], (float)h1[6], (float)h1[7]);
    float rc = r[ci];
    a0.x = fmaf(rc, uh[ci][0].x, a0.x); a0.y = fmaf(rc, uh[ci][0].y, a0.y);
    a0.z = fmaf(rc, uh[ci][0].z, a0.z); a0.w = fmaf(rc, uh[ci][0].w, a0.w);
    a1.x = fmaf(rc, uh[ci][1].x, a1.x); a1.y = fmaf(rc, uh[ci][1].y, a1.y);
    a1.z = fmaf(rc, uh[ci][1].z, a1.z); a1.w = fmaf(rc, uh[ci][1].w, a1.w);
    a2.x = fmaf(rc, uh[ci][2].x, a2.x); a2.y = fmaf(rc, uh[ci][2].y, a2.y);
    a2.z = fmaf(rc, uh[ci][2].z, a2.z); a2.w = fmaf(rc, uh[ci][2].w, a2.w);
    a3.x = fmaf(rc, uh[ci][3].x, a3.x); a3.y = fmaf(rc, uh[ci][3].y, a3.y);
    a3.z = fmaf(rc, uh[ci][3].z, a3.z); a3.w = fmaf(rc, uh[ci][3].w, a3.w);
  }

  float nsq = a0.x*a0.x + a0.y*a0.y + a0.z*a0.z + a0.w*a0.w
            + a1.x*a1.x + a1.y*a1.y + a1.z*a1.z + a1.w*a1.w
            + a2.x*a2.x + a2.y*a2.y + a2.z*a2.z + a2.w*a2.w
            + a3.x*a3.x + a3.y*a3.y + a3.z*a3.z + a3.w*a3.w;
  float scale = nsq / (1.f + nsq) / sqrtf(nsq + 1e-9f);
  a0.x *= scale; a0.y *= scale; a0.z *= scale; a0.w *= scale;
  a1.x *= scale; a1.y *= scale; a1.z *= scale; a1.w *= scale;
  a2.x *= scale; a2.y *= scale; a2.z *= scale; a2.w *= scale;
  a3.x *= scale; a3.y *= scale; a3.z *= scale; a3.w *= scale;

  if (last) {
    float* vp = vout + (size_t)(n * COo + co) * DOo * HW + p;
    vp[0*HW]=a0.x; vp[1*HW]=a0.y; vp[2*HW]=a0.z; vp[3*HW]=a0.w;
    vp[4*HW]=a1.x; vp[5*HW]=a1.y; vp[6*HW]=a1.z; vp[7*HW]=a1.w;
    vp[8*HW]=a2.x; vp[9*HW]=a2.y; vp[10*HW]=a2.z; vp[11*HW]=a2.w;
    vp[12*HW]=a3.x; vp[13*HW]=a3.y; vp[14*HW]=a3.z; vp[15*HW]=a3.w;
  } else {
#pragma unroll
    for (int ci = 0; ci < CIc; ++ci) {
      float dot = uh[ci][0].x*a0.x + uh[ci][0].y*a0.y + uh[ci][0].z*a0.z + uh[ci][0].w*a0.w
                + uh[ci][1].x*a1.x + uh[ci][1].y*a1.y + uh[ci][1].z*a1.z + uh[ci][1].w*a1.w
                + uh[ci][2].x*a2.x + uh[ci][2].y*a2.y + uh[ci][2].z*a2.z + uh[ci][2].w*a2.w
                + uh[ci][3].x*a3.x + uh[ci][3].y*a3.y + uh[ci][3].z*a3.z + uh[ci][3].w*a3.w;
      bout[(size_t)((n * CIc + ci) * COo + co) * HW + p] = bl[ci] + dot;
    }
  }
}

// ------------------------------------------------------------------ launch
extern "C" void kernel_launch(void* const* d_in, const int* in_sizes, int n_in,
                              void* d_out, int out_size, void* d_ws, size_t ws_size,
                              hipStream_t stream) {
  const float* u = (const float*)d_in[0];
  const float* w = (const float*)d_in[1];
  float* out = (float*)d_out;
  char* wsb  = (char*)d_ws;

  _Float16*  uhat = (_Float16*)(wsb + OFFB_UHAT);
  float*     b    = (float*)(wsb + OFFB_B);
  float*     bm   = (float*)(wsb + OFFB_BM);
  float*     is   = (float*)(wsb + OFFB_IS);
  _Float16*  uphi = (_Float16*)(wsb + OFFB_UPHI);
  _Float16*  uplo = (_Float16*)(wsb + OFFB_UPLO);
  _Float16*  whiT = (_Float16*)(wsb + OFFB_WHI);
  _Float16*  wloT = (_Float16*)(wsb + OFFB_WLO);

  prep_u_k<<<(NN * CIc * 52 * 52 + 255) / 256, 256, 0, stream>>>(u, uphi, uplo);
  prep_w_k<<<(CIc * COo * DOo * 28 + 255) / 256, 256, 0, stream>>>(w, whiT, wloT);
  conv_mfma_k<<<NN * CIc * 4, 512, 0, stream>>>(uphi, uplo, whiT, wloT, uhat);

  const int route_grid = (NN * COo * HW) / 256;   // 1152

  routing_stats_k<<<NN * CIc, 256, 0, stream>>>(b, bm, is, 1);
  fused_route_k<<<route_grid, 256, 0, stream>>>(b, bm, is, uhat, b, out, 1, 0);

  routing_stats_k<<<NN * CIc, 256, 0, stream>>>(b, bm, is, 0);
  fused_route_k<<<route_grid, 256, 0, stream>>>(b, bm, is, uhat, b, out, 0, 0);

  routing_stats_k<<<NN * CIc, 256, 0, stream>>>(b, bm, is, 0);
  fused_route_k<<<route_grid, 256, 0, stream>>>(b, bm, is, uhat, b, out, 0, 1);
}

// Round 5
// 130.970 us; speedup vs baseline: 2.9201x; 1.2020x over previous
//
#include <hip/hip_runtime.h>
#include <math.h>

// Problem constants
#define NN  8
#define CIc 8
#define DIc 8
#define Hh  48
#define Ww  48
#define COo 16
#define DOo 16
#define HW  2304      // 48*48

typedef _Float16 f16x8 __attribute__((ext_vector_type(8)));
typedef _Float16 f16x4 __attribute__((ext_vector_type(4)));
typedef float f32x4 __attribute__((ext_vector_type(4)));

// ---------------- workspace layout (byte offsets) ----------------
// uhat : 37,748,736 f16 =  75,497,472 B   [n,ci,co,p,do]
// b    :  2,359,296 f32 =   9,437,184 B
// bm   :    147,456 f32 =     589,824 B
// is   :    147,456 f32 =     589,824 B
// u16  :  1,384,448 f16 =   2,768,896 B   [n,ci,row52,col52,di]
// w16  :    458,752 f16 =     917,504 B   [ci,co,do,k224]  k = tap*8+di
#define OFFB_UHAT 0
#define OFFB_B    75497472
#define OFFB_BM   84934656
#define OFFB_IS   85524480
#define OFFB_U16  86114304
#define OFFB_W16  88883200

// ---------------------------------------------------- prep u (pad + fp16)
__global__ __launch_bounds__(256) void prep_u_k(const float* __restrict__ u,
                                                _Float16* __restrict__ u16) {
  int idx = blockIdx.x * 256 + threadIdx.x;
  if (idx >= NN * CIc * 52 * 52) return;
  int col = idx % 52;
  int t = idx / 52;
  int row = t % 52;
  t /= 52;                        // t = n*CIc + ci
  int h = row - 2, w = col - 2;
  f16x8 hv;
#pragma unroll
  for (int di = 0; di < 8; ++di) {
    float val = 0.f;
    if (h >= 0 && h < Hh && w >= 0 && w < Ww)
      val = u[((size_t)t * DIc + di) * HW + h * Ww + w];
    hv[di] = (_Float16)val;
  }
  *(f16x8*)(u16 + (size_t)idx * 8) = hv;
}

// ---------------------------------------------------- prep w (reorder + fp16)
// [ci][co][do][k=tap*8+di], taps 25..27 zero-padded.
__global__ __launch_bounds__(256) void prep_w_k(const float* __restrict__ w,
                                                _Float16* __restrict__ w16) {
  int idx = blockIdx.x * 256 + threadIdx.x;
  if (idx >= CIc * COo * DOo * 28) return;
  int tap = idx % 28;
  int t = idx / 28;
  int dd = t % DOo;
  t /= DOo;
  int co = t % COo;
  int ci = t / COo;
  f16x8 hv;
#pragma unroll
  for (int di = 0; di < 8; ++di) {
    float val = 0.f;
    if (tap < 25)
      val = w[((size_t)(ci * 256 + co * 16 + dd)) * 200 + di * 25 + tap];
    hv[di] = (_Float16)val;
  }
  *(f16x8*)(w16 + ((size_t)(ci * COo + co) * DOo + dd) * 224 + tap * 8) = hv;
}

// ---------------------------------------------------------------- MFMA conv
// Per (n,ci): C[256 (co,do), 2304 p] = W[256,224] x im2col(u)[224,2304], pure fp16.
// Block = (n, ci, co-half, pos-eighth): 256 thr / 4 waves; wave = 2 co.
// One B-fragment LDS read feeds 2 MFMAs (both co). Weights in registers.
__global__ __launch_bounds__(256, 4) void conv_mfma_k(const _Float16* __restrict__ u16,
                                                      const _Float16* __restrict__ w16,
                                                      _Float16* __restrict__ uhat) {
  __shared__ _Float16 s_u[11 * 52 * 8];   // 9,152 B (row 10 = zeros)

  const int blk = blockIdx.x;
  const int pe = blk & 7;          // pos-eighth: output rows pe*6 .. pe*6+5
  const int ch = (blk >> 3) & 1;   // co half
  const int ci = (blk >> 4) & 7;
  const int n  = blk >> 7;
  const int tid = threadIdx.x;
  const int wv = tid >> 6, lane = tid & 63;
  const int l15 = lane & 15, l4 = lane >> 4;

  // stage padded rows pe*6 .. pe*6+9 (520 f16x8 slots) + zero row 10
  const _Float16* gu = u16 + ((size_t)(n * CIc + ci) * 2704 + pe * 6 * 52) * 8;
  for (int it = tid; it < 520; it += 256)
    *(f16x8*)(s_u + it * 8) = *(const f16x8*)(gu + it * 8);
  if (tid < 52) {
    f16x8 z = {0, 0, 0, 0, 0, 0, 0, 0};
    *(f16x8*)(s_u + (520 + tid) * 8) = z;
  }

  // per-wave weight A-fragments for 2 co -> registers (7 ksteps each)
  const int co0 = ch * 8 + wv * 2;
  f16x8 a[2][7];
#pragma unroll
  for (int c = 0; c < 2; ++c) {
    const _Float16* wb = w16 + ((size_t)(ci * COo + co0 + c) * DOo + l15) * 224 + l4 * 8;
#pragma unroll
    for (int ks = 0; ks < 7; ++ks) a[c][ks] = *(const f16x8*)(wb + ks * 32);
  }
  __syncthreads();

  _Float16* ob = uhat + (size_t)((n * CIc + ci) * COo + co0) * (HW * 16);

  for (int chunk = 0; chunk < 6; ++chunk) {
    f32x4 acc[2][3];
#pragma unroll
    for (int c = 0; c < 2; ++c)
#pragma unroll
      for (int nt = 0; nt < 3; ++nt) {
        f32x4 z = {0.f, 0.f, 0.f, 0.f};
        acc[c][nt] = z;
      }
#pragma unroll
    for (int ks = 0; ks < 7; ++ks) {
      const int tap = ks * 4 + l4;       // 0..27 (25..27: zero weights)
      const int dy = tap / 5;            // 0..5
      const int dx = tap - dy * 5;
      const int row = chunk + dy;        // <= 10
#pragma unroll
      for (int nt = 0; nt < 3; ++nt) {
        const int col = nt * 16 + dx + l15;
        f16x8 bfrag = *(const f16x8*)(s_u + (row * 52 + col) * 8);
        acc[0][nt] = __builtin_amdgcn_mfma_f32_16x16x32_f16(a[0][ks], bfrag, acc[0][nt], 0, 0, 0);
        acc[1][nt] = __builtin_amdgcn_mfma_f32_16x16x32_f16(a[1][ks], bfrag, acc[1][nt], 0, 0, 0);
      }
    }
    // C frag: col = l15 = position, row = l4*4+j = do  -> f16x4 store
#pragma unroll
    for (int c = 0; c < 2; ++c)
#pragma unroll
      for (int nt = 0; nt < 3; ++nt) {
        int p = pe * 288 + chunk * 48 + nt * 16 + l15;
        f32x4 vv = acc[c][nt];
        f16x4 hv;
        hv[0] = (_Float16)vv[0]; hv[1] = (_Float16)vv[1];
        hv[2] = (_Float16)vv[2]; hv[3] = (_Float16)vv[3];
        *(f16x4*)(ob + (size_t)c * (HW * 16) + (size_t)p * 16 + l4 * 4) = hv;
      }
  }
}

// ----------------------------------------------------- routing stats (separable)
__global__ __launch_bounds__(256) void routing_stats_k(const float* __restrict__ b,
                                                       float* __restrict__ bmax,
                                                       float* __restrict__ isum,
                                                       int zb) {
  __shared__ float m_lds[HW];
  __shared__ float t_lds[HW];
  const int blk = blockIdx.x;   // n*CIc + ci
  const int tid = threadIdx.x;
  const float* bp = b + (size_t)blk * COo * HW;

  for (int p = tid; p < HW; p += 256) {
    float m;
    if (zb) {
      m = 0.f;
    } else {
      m = -INFINITY;
      for (int co = 0; co < COo; ++co) m = fmaxf(m, bp[(size_t)co * HW + p]);
    }
    m_lds[p] = m;
  }
  __syncthreads();
  for (int p = tid; p < HW; p += 256) {
    int h = p / Ww, w = p % Ww;
    float v = -INFINITY;
#pragma unroll
    for (int dx = -2; dx <= 2; ++dx) {
      int ww2 = w + dx;
      if (ww2 >= 0 && ww2 < Ww) v = fmaxf(v, m_lds[h * Ww + ww2]);
    }
    t_lds[p] = v;
  }
  __syncthreads();
  for (int p = tid; p < HW; p += 256) {
    int h = p / Ww, w = p % Ww;
    float bm = -INFINITY;
#pragma unroll
    for (int dy = -2; dy <= 2; ++dy) {
      int hh = h + dy;
      if (hh >= 0 && hh < Hh) bm = fmaxf(bm, t_lds[hh * Ww + w]);
    }
    bmax[(size_t)blk * HW + p] = bm;
    float cs;
    if (zb) {
      cs = 16.f;
    } else {
      cs = 0.f;
      for (int co = 0; co < COo; ++co)
        cs += __expf(bp[(size_t)co * HW + p] - bm);
    }
    m_lds[p] = cs;
  }
  __syncthreads();
  for (int p = tid; p < HW; p += 256) {
    int h = p / Ww, w = p % Ww;
    float s = 0.f;
#pragma unroll
    for (int dx = -2; dx <= 2; ++dx) {
      int ww2 = w + dx;
      if (ww2 >= 0 && ww2 < Ww) s += m_lds[h * Ww + ww2];
    }
    t_lds[p] = s;
  }
  __syncthreads();
  for (int p = tid; p < HW; p += 256) {
    int h = p / Ww, w = p % Ww;
    float s = 0.f;
#pragma unroll
    for (int dy = -2; dy <= 2; ++dy) {
      int hh = h + dy;
      if (hh >= 0 && hh < Hh) s += t_lds[hh * Ww + w];
    }
    isum[(size_t)blk * HW + p] = 1.f / s;
  }
}

// ------------------------------------------- fused p + squash + b-update
__global__ __launch_bounds__(256, 2) void fused_route_k(const float* __restrict__ b,
                                                        const float* __restrict__ bmax,
                                                        const float* __restrict__ isum,
                                                        const _Float16* __restrict__ uhat,
                                                        float* __restrict__ bout,
                                                        float* __restrict__ vout,
                                                        int zb, int last) {
  int idx = blockIdx.x * 256 + threadIdx.x;   // (n*COo+co)*HW + p
  int p  = idx % HW;
  int t  = idx / HW;
  int co = t % COo;
  int n  = t / COo;

  float bl[CIc], r[CIc];
#pragma unroll
  for (int ci = 0; ci < CIc; ++ci) {
    int s = n * CIc + ci;
    bl[ci] = zb ? 0.f : b[(size_t)(s * COo + co) * HW + p];
    r[ci]  = __expf(bl[ci] - bmax[(size_t)s * HW + p]) * isum[(size_t)s * HW + p];
  }

  float4 uh[CIc][4];
  float4 a0 = make_float4(0.f, 0.f, 0.f, 0.f);
  float4 a1 = a0, a2 = a0, a3 = a0;
#pragma unroll
  for (int ci = 0; ci < CIc; ++ci) {
    const f16x8* uhp = (const f16x8*)(uhat +
        ((size_t)((n * CIc + ci) * COo + co) * HW + p) * DOo);
    f16x8 h0 = uhp[0], h1 = uhp[1];
    uh[ci][0] = make_float4((float)h0[0], (float)h0[1], (float)h0[2], (float)h0[3]);
    uh[ci][1] = make_float4((float)h0[4], (float)h0[5], (float)h0[6], (float)h0[7]);
    uh[ci][2] = make_float4((float)h1[0], (float)h1[1], (float)h1[2], (float)h1[3]);
    uh[ci][3] = make_float4((float)h1[4], (float)h1[5], (float)h1[6], (float)h1[7]);
    float rc = r[ci];
    a0.x = fmaf(rc, uh[ci][0].x, a0.x); a0.y = fmaf(rc, uh[ci][0].y, a0.y);
    a0.z = fmaf(rc, uh[ci][0].z, a0.z); a0.w = fmaf(rc, uh[ci][0].w, a0.w);
    a1.x = fmaf(rc, uh[ci][1].x, a1.x); a1.y = fmaf(rc, uh[ci][1].y, a1.y);
    a1.z = fmaf(rc, uh[ci][1].z, a1.z); a1.w = fmaf(rc, uh[ci][1].w, a1.w);
    a2.x = fmaf(rc, uh[ci][2].x, a2.x); a2.y = fmaf(rc, uh[ci][2].y, a2.y);
    a2.z = fmaf(rc, uh[ci][2].z, a2.z); a2.w = fmaf(rc, uh[ci][2].w, a2.w);
    a3.x = fmaf(rc, uh[ci][3].x, a3.x); a3.y = fmaf(rc, uh[ci][3].y, a3.y);
    a3.z = fmaf(rc, uh[ci][3].z, a3.z); a3.w = fmaf(rc, uh[ci][3].w, a3.w);
  }

  float nsq = a0.x*a0.x + a0.y*a0.y + a0.z*a0.z + a0.w*a0.w
            + a1.x*a1.x + a1.y*a1.y + a1.z*a1.z + a1.w*a1.w
            + a2.x*a2.x + a2.y*a2.y + a2.z*a2.z + a2.w*a2.w
            + a3.x*a3.x + a3.y*a3.y + a3.z*a3.z + a3.w*a3.w;
  float scale = nsq / (1.f + nsq) / sqrtf(nsq + 1e-9f);
  a0.x *= scale; a0.y *= scale; a0.z *= scale; a0.w *= scale;
  a1.x *= scale; a1.y *= scale; a1.z *= scale; a1.w *= scale;
  a2.x *= scale; a2.y *= scale; a2.z *= scale; a2.w *= scale;
  a3.x *= scale; a3.y *= scale; a3.z *= scale; a3.w *= scale;

  if (last) {
    float* vp = vout + (size_t)(n * COo + co) * DOo * HW + p;
    vp[0*HW]=a0.x; vp[1*HW]=a0.y; vp[2*HW]=a0.z; vp[3*HW]=a0.w;
    vp[4*HW]=a1.x; vp[5*HW]=a1.y; vp[6*HW]=a1.z; vp[7*HW]=a1.w;
    vp[8*HW]=a2.x; vp[9*HW]=a2.y; vp[10*HW]=a2.z; vp[11*HW]=a2.w;
    vp[12*HW]=a3.x; vp[13*HW]=a3.y; vp[14*HW]=a3.z; vp[15*HW]=a3.w;
  } else {
#pragma unroll
    for (int ci = 0; ci < CIc; ++ci) {
      float dot = uh[ci][0].x*a0.x + uh[ci][0].y*a0.y + uh[ci][0].z*a0.z + uh[ci][0].w*a0.w
                + uh[ci][1].x*a1.x + uh[ci][1].y*a1.y + uh[ci][1].z*a1.z + uh[ci][1].w*a1.w
                + uh[ci][2].x*a2.x + uh[ci][2].y*a2.y + uh[ci][2].z*a2.z + uh[ci][2].w*a2.w
                + uh[ci][3].x*a3.x + uh[ci][3].y*a3.y + uh[ci][3].z*a3.z + uh[ci][3].w*a3.w;
      bout[(size_t)((n * CIc + ci) * COo + co) * HW + p] = bl[ci] + dot;
    }
  }
}

// ------------------------------------------------------------------ launch
extern "C" void kernel_launch(void* const* d_in, const int* in_sizes, int n_in,
                              void* d_out, int out_size, void* d_ws, size_t ws_size,
                              hipStream_t stream) {
  const float* u = (const float*)d_in[0];
  const float* w = (const float*)d_in[1];
  float* out = (float*)d_out;
  char* wsb  = (char*)d_ws;

  _Float16*  uhat = (_Float16*)(wsb + OFFB_UHAT);
  float*     b    = (float*)(wsb + OFFB_B);
  float*     bm   = (float*)(wsb + OFFB_BM);
  float*     is   = (float*)(wsb + OFFB_IS);
  _Float16*  u16  = (_Float16*)(wsb + OFFB_U16);
  _Float16*  w16  = (_Float16*)(wsb + OFFB_W16);

  prep_u_k<<<(NN * CIc * 52 * 52 + 255) / 256, 256, 0, stream>>>(u, u16);
  prep_w_k<<<(CIc * COo * DOo * 28 + 255) / 256, 256, 0, stream>>>(w, w16);
  conv_mfma_k<<<NN * CIc * 2 * 8, 256, 0, stream>>>(u16, w16, uhat);

  const int route_grid = (NN * COo * HW) / 256;   // 1152

  routing_stats_k<<<NN * CIc, 256, 0, stream>>>(b, bm, is, 1);
  fused_route_k<<<route_grid, 256, 0, stream>>>(b, bm, is, uhat, b, out, 1, 0);

  routing_stats_k<<<NN * CIc, 256, 0, stream>>>(b, bm, is, 0);
  fused_route_k<<<route_grid, 256, 0, stream>>>(b, bm, is, uhat, b, out, 0, 0);

  routing_stats_k<<<NN * CIc, 256, 0, stream>>>(b, bm, is, 0);
  fused_route_k<<<route_grid, 256, 0, stream>>>(b, bm, is, uhat, b, out, 0, 1);
}